// Round 7
// baseline (135.157 us; speedup 1.0000x reference)
//
#include <hip/hip_runtime.h>
#include <hip/hip_bf16.h>
#include <math.h>

constexpr int BB = 4;     // batch
constexpr int TT = 2048;  // sequence
constexpr int CC = 768;   // channels
constexpr int HH = 64;    // head dim
constexpr int NSPLIT = 8; // attention s-splits

// Softmax is computed in base-2: q carries 0.125*log2(e), exp -> exp2.
#define QSCALE 0.1803368801111204f   // 0.125 * log2(e)

typedef __attribute__((ext_vector_type(8))) short bf16x8;   // 8 bf16 = 4 VGPR
typedef __attribute__((ext_vector_type(4))) float f32x4;    // MFMA C/D

__device__ inline ushort f2bf(float f) {   // fp32 -> bf16 RNE (scalar)
    uint u = __float_as_uint(f);
    u += 0x7fffu + ((u >> 16) & 1u);
    return (ushort)(u >> 16);
}

__device__ inline float fexp2(float x) { return __builtin_amdgcn_exp2f(x); }

__device__ inline bf16x8 cvt8(const float4 a, const float4 b) {  // packed cvt
    union { bf16x8 v; __hip_bfloat162 h[4]; } u;
    u.h[0] = __float22bfloat162_rn(make_float2(a.x, a.y));
    u.h[1] = __float22bfloat162_rn(make_float2(a.z, a.w));
    u.h[2] = __float22bfloat162_rn(make_float2(b.x, b.y));
    u.h[3] = __float22bfloat162_rn(make_float2(b.z, b.w));
    return u.v;
}

// ---------------------------------------------------------------------------
// prep_w: W[768][64] fp32 -> Wt[mat][n][768] bf16 (transposed, k-contiguous)
// ---------------------------------------------------------------------------
__global__ __launch_bounds__(256) void prep_w(const float* __restrict__ Wq,
                                              const float* __restrict__ Wk,
                                              const float* __restrict__ Wv,
                                              ushort* __restrict__ Wt) {
    const int k0  = blockIdx.x * 64;
    const int mat = blockIdx.y;
    const float* W = (mat == 0) ? Wq : (mat == 1) ? Wk : Wv;
    __shared__ ushort tile[64 * 66];
    const int tid = threadIdx.x;

    for (int i = tid; i < 1024; i += 256) {
        int kk = i >> 4, c = i & 15;
        float4 f = ((const float4*)W)[(k0 + kk) * 16 + c];
        ushort* d = &tile[kk * 66 + c * 4];
        d[0] = f2bf(f.x); d[1] = f2bf(f.y); d[2] = f2bf(f.z); d[3] = f2bf(f.w);
    }
    __syncthreads();
    for (int i = tid; i < 512; i += 256) {
        int n = i >> 3, c8 = i & 7;
        bf16x8 v;
        #pragma unroll
        for (int j = 0; j < 8; ++j)
            ((ushort*)&v)[j] = tile[(c8 * 8 + j) * 66 + n];
        *(bf16x8*)&Wt[(size_t)(mat * 64 + n) * CC + k0 + c8 * 8] = v;
    }
}

// ---------------------------------------------------------------------------
// qkv_mfma: 16 rows x 192 cols per block, 4 waves col-split, explicit
// 4-deep register prefetch pipeline on x and Wt (~20 loads in flight/wave).
// q pre-scaled by 0.125*log2e (base-2 softmax downstream).
// ---------------------------------------------------------------------------
__global__ __launch_bounds__(256) void qkv_mfma(const float* __restrict__ x,
                                                const ushort* __restrict__ Wt,
                                                ushort* __restrict__ qg,
                                                ushort* __restrict__ kg,
                                                ushort* __restrict__ vtg) {
    __shared__ ushort vts[64 * 24];      // [h][t-local 0..15], stride 24
    const int tid  = threadIdx.x;
    const int row0 = blockIdx.x * 16;
    const int lane = tid & 63, w = tid >> 6;
    const int l15  = lane & 15, quad = lane >> 4;
    const int cg   = w * 48;             // this wave's first output col

    f32x4 acc[3];
    #pragma unroll
    for (int i = 0; i < 3; ++i) acc[i] = (f32x4){0.f, 0.f, 0.f, 0.f};

    const float*  xrow  = x + (size_t)(row0 + l15) * CC;
    const ushort* wbase = Wt + (size_t)(cg + l15) * CC + quad * 8;

    float4 xb[4][2];
    bf16x8 wb[4][3];
    #pragma unroll
    for (int i = 0; i < 4; ++i) {        // prime the pipeline: kc = 0..3
        const float4* xp = (const float4*)(xrow + i * 32) + quad * 2;
        xb[i][0] = xp[0];
        xb[i][1] = xp[1];
        #pragma unroll
        for (int nt = 0; nt < 3; ++nt)
            wb[i][nt] = *(const bf16x8*)(wbase + (size_t)nt * 16 * CC + i * 32);
    }

    #pragma unroll
    for (int kc = 0; kc < 24; ++kc) {
        const int cur = kc & 3;
        bf16x8 a  = cvt8(xb[cur][0], xb[cur][1]);
        bf16x8 w0 = wb[cur][0], w1 = wb[cur][1], w2 = wb[cur][2];
        const int nx = kc + 4;
        if (nx < 24) {                   // refill slot: loads issue before MFMAs
            const float4* xp = (const float4*)(xrow + nx * 32) + quad * 2;
            xb[cur][0] = xp[0];
            xb[cur][1] = xp[1];
            #pragma unroll
            for (int nt = 0; nt < 3; ++nt)
                wb[cur][nt] = *(const bf16x8*)(wbase + (size_t)nt * 16 * CC + nx * 32);
        }
        acc[0] = __builtin_amdgcn_mfma_f32_16x16x32_bf16(a, w0, acc[0], 0, 0, 0);
        acc[1] = __builtin_amdgcn_mfma_f32_16x16x32_bf16(a, w1, acc[1], 0, 0, 0);
        acc[2] = __builtin_amdgcn_mfma_f32_16x16x32_bf16(a, w2, acc[2], 0, 0, 0);
    }

    // epilogue: C layout row = quad*4+r (16-row tile), col = l15 (+16*nt)
    #pragma unroll
    for (int nt = 0; nt < 3; ++nt) {
        int n = cg + nt * 16 + l15;
        #pragma unroll
        for (int r = 0; r < 4; ++r) {
            int row = row0 + quad * 4 + r;
            float vacc = acc[nt][r];
            if (n < 64)       qg[(size_t)row * HH + n] = f2bf(vacc * QSCALE);
            else if (n < 128) kg[(size_t)row * HH + (n - 64)] = f2bf(vacc);
            else              vts[(n - 128) * 24 + (quad * 4 + r)] = f2bf(vacc);
        }
    }
    __syncthreads();
    if (tid < 128) {   // cooperative write vt[b][h][t0..t0+15]
        int h = tid >> 1, p = tid & 1;
        int b = row0 >> 11, tl = row0 & 2047;
        bf16x8 v = *(const bf16x8*)&vts[h * 24 + p * 8];
        *(bf16x8*)&vtg[(size_t)b * (HH * TT) + (size_t)h * TT + tl + p * 8] = v;
    }
}

// ---------------------------------------------------------------------------
// attn_split: 32-query tile (2 waves) x 8-way s-split. 2048 blocks.
// K prefetched one step ahead; V issued before softmax. Zero __syncthreads.
// Softmax in base-2 (q carries log2e); single v_exp_f32 per element.
// ---------------------------------------------------------------------------
__global__ __launch_bounds__(128) void attn_split(const ushort* __restrict__ qg,
                                                  const ushort* __restrict__ kg,
                                                  const ushort* __restrict__ vtg,
                                                  float* __restrict__ Op,
                                                  float* __restrict__ ml) {
    const int qt2 = blockIdx.x, b = blockIdx.y, split = blockIdx.z;
    const int tid  = threadIdx.x;
    const int lane = tid & 63, w = tid >> 6;
    const int l15  = lane & 15, quad = lane >> 4;
    const int t0   = qt2 * 32;
    const int pidx = ((b * 64 + qt2) << 3) + split;

    const int ntile = (qt2 >> 1) + 1;     // 64-wide s-tiles covering s <= t0+31
    const int lo = (ntile * split) >> 3;
    const int hi = (ntile * (split + 1)) >> 3;

    if (lo >= hi) {   // empty split: zero partials
        float4 z = (float4){0.f, 0.f, 0.f, 0.f};
        float4* op4 = (float4*)(Op + (size_t)pidx * 2048);
        #pragma unroll
        for (int j = 0; j < 4; ++j) op4[tid * 4 + j] = z;
        if (tid < 32) {
            ml[pidx * 64 + tid]      = -1e30f;
            ml[pidx * 64 + 32 + tid] = 0.f;
        }
        return;
    }

    __shared__ ushort Ps[2][16 * 72];

    // Q fragments direct from global (q pre-scaled by 0.125*log2e)
    const ushort* qp = &qg[(size_t)(b * TT + t0 + w * 16 + l15) * HH + quad * 8];
    bf16x8 qa0 = *(const bf16x8*)qp;
    bf16x8 qa1 = *(const bf16x8*)(qp + 32);

    const ushort* kbb = &kg[(size_t)(b * TT + l15) * HH + quad * 8];
    const ushort* vbb = &vtg[(size_t)b * (HH * TT) + (size_t)l15 * TT + quad * 8];

    f32x4 po[4];
    #pragma unroll
    for (int i = 0; i < 4; ++i) po[i] = (f32x4){0.f, 0.f, 0.f, 0.f};
    float mrun[4] = {-1e30f, -1e30f, -1e30f, -1e30f};
    float lrun[4] = {0.f, 0.f, 0.f, 0.f};

    bf16x8 kb[8], vb[8];
    #pragma unroll
    for (int nt = 0; nt < 4; ++nt) {     // prime K for st = lo
        const ushort* kp = kbb + (size_t)(lo * 64 + nt * 16) * HH;
        kb[2 * nt]     = *(const bf16x8*)kp;
        kb[2 * nt + 1] = *(const bf16x8*)(kp + 32);
    }

    for (int st = lo; st < hi; ++st) {
        // S = Q K^T (uses prefetched kb)
        f32x4 sf[4];
        #pragma unroll
        for (int nt = 0; nt < 4; ++nt) {
            f32x4 z = (f32x4){0.f, 0.f, 0.f, 0.f};
            z = __builtin_amdgcn_mfma_f32_16x16x32_bf16(qa0, kb[2 * nt], z, 0, 0, 0);
            sf[nt] = __builtin_amdgcn_mfma_f32_16x16x32_bf16(qa1, kb[2 * nt + 1], z, 0, 0, 0);
        }
        // prefetch next K (latency hidden under softmax + PV)
        if (st + 1 < hi) {
            #pragma unroll
            for (int nt = 0; nt < 4; ++nt) {
                const ushort* kp = kbb + (size_t)((st + 1) * 64 + nt * 16) * HH;
                kb[2 * nt]     = *(const bf16x8*)kp;
                kb[2 * nt + 1] = *(const bf16x8*)(kp + 32);
            }
        }
        // issue V loads for this step (consumed after softmax + P transpose)
        #pragma unroll
        for (int jj = 0; jj < 4; ++jj) {
            const ushort* vp = vbb + (size_t)(jj * 16) * TT + st * 64;
            vb[2 * jj]     = *(const bf16x8*)vp;
            vb[2 * jj + 1] = *(const bf16x8*)(vp + 32);
        }

        // causal mask (diagonal tile lives in the last split) + online softmax
        float p[4][4];
        float rm[4] = {-1e30f, -1e30f, -1e30f, -1e30f};
        if (st == ntile - 1) {
            #pragma unroll
            for (int nt = 0; nt < 4; ++nt) {
                int s_abs = st * 64 + nt * 16 + l15;
                #pragma unroll
                for (int r = 0; r < 4; ++r) {
                    int t_abs = t0 + w * 16 + quad * 4 + r;
                    float v = (s_abs > t_abs) ? -1e30f : sf[nt][r];
                    p[nt][r] = v;
                    rm[r] = fmaxf(rm[r], v);
                }
            }
        } else {
            #pragma unroll
            for (int nt = 0; nt < 4; ++nt)
                #pragma unroll
                for (int r = 0; r < 4; ++r) {
                    p[nt][r] = sf[nt][r];
                    rm[r] = fmaxf(rm[r], sf[nt][r]);
                }
        }
        float alpha[4], rs[4] = {0.f, 0.f, 0.f, 0.f};
        #pragma unroll
        for (int r = 0; r < 4; ++r) {
            float v = rm[r];
            v = fmaxf(v, __shfl_xor(v, 1, 64));
            v = fmaxf(v, __shfl_xor(v, 2, 64));
            v = fmaxf(v, __shfl_xor(v, 4, 64));
            v = fmaxf(v, __shfl_xor(v, 8, 64));
            float mnew = fmaxf(mrun[r], v);
            alpha[r] = fexp2(mrun[r] - mnew);
            mrun[r] = mnew;
        }
        #pragma unroll
        for (int nt = 0; nt < 4; ++nt)
            #pragma unroll
            for (int r = 0; r < 4; ++r) {
                float e = fexp2(p[nt][r] - mrun[r]);
                p[nt][r] = e;
                rs[r] += e;
            }
        #pragma unroll
        for (int r = 0; r < 4; ++r) {
            float v = rs[r];
            v += __shfl_xor(v, 1, 64);
            v += __shfl_xor(v, 2, 64);
            v += __shfl_xor(v, 4, 64);
            v += __shfl_xor(v, 8, 64);
            lrun[r] = lrun[r] * alpha[r] + v;
        }
        #pragma unroll
        for (int jj = 0; jj < 4; ++jj)
            #pragma unroll
            for (int r = 0; r < 4; ++r)
                po[jj][r] *= alpha[r];

        // P: C-layout regs -> per-wave LDS -> A-layout frags (no barrier)
        #pragma unroll
        for (int nt = 0; nt < 4; ++nt)
            #pragma unroll
            for (int r = 0; r < 4; ++r)
                Ps[w][(quad * 4 + r) * 72 + nt * 16 + l15] = f2bf(p[nt][r]);
        bf16x8 pa0 = *(const bf16x8*)&Ps[w][l15 * 72 + quad * 8];
        bf16x8 pa1 = *(const bf16x8*)&Ps[w][l15 * 72 + 32 + quad * 8];

        // O += P V (uses vb issued before softmax)
        #pragma unroll
        for (int jj = 0; jj < 4; ++jj) {
            po[jj] = __builtin_amdgcn_mfma_f32_16x16x32_bf16(pa0, vb[2 * jj], po[jj], 0, 0, 0);
            po[jj] = __builtin_amdgcn_mfma_f32_16x16x32_bf16(pa1, vb[2 * jj + 1], po[jj], 0, 0, 0);
        }
    }

    // write partials: unnormalized O + per-row m, l
    #pragma unroll
    for (int jj = 0; jj < 4; ++jj)
        #pragma unroll
        for (int r = 0; r < 4; ++r)
            Op[(size_t)pidx * 2048 + (w * 16 + quad * 4 + r) * 64 + jj * 16 + l15] =
                po[jj][r];
    if (l15 == 0) {
        #pragma unroll
        for (int r = 0; r < 4; ++r) {
            int row = w * 16 + quad * 4 + r;
            ml[pidx * 64 + row]      = mrun[r];
            ml[pidx * 64 + 32 + row] = lrun[r];
        }
    }
}

// ---------------------------------------------------------------------------
// attn_merge: combine NSPLIT partials per row; one wave per output row.
// ---------------------------------------------------------------------------
__global__ __launch_bounds__(256) void attn_merge(const float* __restrict__ Op,
                                                  const float* __restrict__ ml,
                                                  float* __restrict__ out) {
    const int tid = threadIdx.x;
    const int w = tid >> 6, lane = tid & 63;
    const int row = blockIdx.x * 4 + w;        // 0..8191
    const int b = row >> 11, t = row & 2047;
    const int qt2 = t >> 5, rl = t & 31;
    const int pbase = ((b * 64 + qt2) << 3);

    float m[NSPLIT], l[NSPLIT];
    #pragma unroll
    for (int i = 0; i < NSPLIT; ++i) {
        m[i] = ml[(pbase + i) * 64 + rl];
        l[i] = ml[(pbase + i) * 64 + 32 + rl];
    }
    float M = -1e30f;
    #pragma unroll
    for (int i = 0; i < NSPLIT; ++i) M = fmaxf(M, m[i]);
    float wgt[NSPLIT], L = 0.f;
    #pragma unroll
    for (int i = 0; i < NSPLIT; ++i) {
        wgt[i] = fexp2(m[i] - M);     // base-2 domain (matches attn_split)
        L += wgt[i] * l[i];
    }
    float acc = 0.f;
    #pragma unroll
    for (int i = 0; i < NSPLIT; ++i)
        acc += wgt[i] * Op[(size_t)(pbase + i) * 2048 + rl * 64 + lane];
    out[(size_t)row * HH + lane] = acc / L;
}

// ---------------------------------------------------------------------------
extern "C" void kernel_launch(void* const* d_in, const int* in_sizes, int n_in,
                              void* d_out, int out_size, void* d_ws, size_t ws_size,
                              hipStream_t stream)
{
    const float* x  = (const float*)d_in[0];
    const float* Wq = (const float*)d_in[1];
    const float* Wk = (const float*)d_in[2];
    const float* Wv = (const float*)d_in[3];
    float* out = (float*)d_out;

    // ws layout: qg 1MB | kg 1MB | vtg 1MB | Wt 288KB | Op 16.8MB | ml 512KB
    ushort* qg  = (ushort*)d_ws;
    ushort* kg  = qg  + (size_t)BB * TT * HH;
    ushort* vtg = kg  + (size_t)BB * TT * HH;
    ushort* Wt  = vtg + (size_t)BB * TT * HH;
    float*  Op  = (float*)(Wt + (size_t)3 * HH * CC);
    float*  ml  = Op + (size_t)2048 * 2048;

    prep_w    <<<dim3(12, 3),           dim3(256), 0, stream>>>(Wq, Wk, Wv, Wt);
    qkv_mfma  <<<dim3((BB * TT) / 16),  dim3(256), 0, stream>>>(x, Wt, qg, kg, vtg);
    attn_split<<<dim3(64, BB, NSPLIT),  dim3(128), 0, stream>>>(qg, kg, vtg, Op, ml);
    attn_merge<<<dim3((BB * TT) / 4),   dim3(256), 0, stream>>>(Op, ml, out);
}